// Round 8
// baseline (3056.773 us; speedup 1.0000x reference)
//
#include <hip/hip_runtime.h>

// ============================================================================
// ACTP two-layer LSTM rollout, persistent-kernel bf16-MFMA implementation.
//
// R13 change: R12 (M=64 B-reuse) + amdgpu_num_vgpr(224) to force the register
// budget the allocator refuses to give via occupancy hints.
//   Evidence (R12 counters): M=64 doubled state (+48 arch) past the 128
//   budget -> WRITE 3.08GB / FETCH 3.5GB scratch, dur 3057us. The allocator
//   spilled to scratch instead of using the idle AGPR half of the unified
//   file (256/wave free at 2 waves/SIMD). Occupancy is LDS-pinned at
//   2 waves/SIMD regardless (1 block/CU), so the 128 target buys nothing.
//   R1-R4 proved launch_bounds/waves_per_eu (occupancy HINTS) don't move
//   the budget; amdgpu_num_vgpr is the explicit override, never tried.
//   Live-set: arch ~174 (b[8] 32 + a 16 + c[2]x2 64 + tmp[2] 32 + temps) +
//   32 AGPR acc = ~206 total; 224 covers it under either attribute
//   semantics and preserves 2 waves/SIMD (224+32 <= 256).
//   Readout: VGPR_Count ~224 & WRITE ~65MB -> expect dur ~800-950us.
//   If VGPR_Count stays 128: attribute ignored -> revert to R11 structure,
//   pursue global_load_lds ring staging instead.
//
// Structure (= R12):
//  - 512 blocks x 512 threads (8 waves), 64 batch rows/block, 19 steps.
//  - Wave q=wid: gate-col-tile jt=q (q==7 idle in LSTM gemms). 4 single-gate
//    passes per cell (f->i->g->o), TWO f32x16 AGPR accumulators (row-tiles),
//    a0/a1[2] + shared b[8] prefetch; B bases scalarized via readfirstlane.
//  - h1/h2 double-buffered in LDS bf16 (64 rows x stride 232), 128KB dynamic.
//    fc1 "out3" aliases dead h1-old.
//  - Weights pre-converted to bf16 fragment-major (frag = 64 lanes x 16B,
//    coalesced 1KB loads), N padded 200->224 (7 jt of 32), K chunks of 16.
//  - fc1/fc2 skipped for context steps 0..8 (outputs unused).
// MFMA v_mfma_f32_32x32x16_bf16 layouts (per cdna4_isa.md):
//   A: m=lane&31, k=8*(lane>>5)+i ; B: n=lane&31, k=8*(lane>>5)+i
//   C/D: col=lane&31, row=(r&3)+8*(r>>2)+4*(lane>>5)
// ============================================================================

typedef short bf16x8 __attribute__((ext_vector_type(8)));
typedef float f32x16 __attribute__((ext_vector_type(16)));

#define NFRAG    1398
#define FRAG_B2  448     // lstm1: 4*7*16 frags
#define FRAG_BF1 1260    // lstm2: 4*7*29 frags
#define FRAG_BF2 1372    // fc1:   7*16 frags ; fc2: 2*13 frags

__device__ __forceinline__ unsigned short f2bf(float f) {
  unsigned int x = __float_as_uint(f);
  x += 0x7fffu + ((x >> 16) & 1u);          // RNE; inputs are finite
  return (unsigned short)(x >> 16);
}
__device__ __forceinline__ float sigf(float x) {
  return __builtin_amdgcn_rcpf(1.f + __expf(-x));   // exp(inf)->inf->rcp->0: safe
}
__device__ __forceinline__ float tanh_f(float x) {
  float e = __expf(2.f * fabsf(x));                 // e>=1, inf handled (t->1)
  float t = 1.f - 2.f * __builtin_amdgcn_rcpf(e + 1.f);
  return copysignf(t, x);
}

// Force a wave-uniform fragment index into an SGPR and build the stream base.
__device__ __forceinline__ const bf16x8* uni_frag(
    const unsigned short* __restrict__ ws, int frag) {
  const int f = __builtin_amdgcn_readfirstlane(frag);
  return (const bf16x8*)(ws + (size_t)f * 512);     // 512 ushort = 1KB/frag
}

// ---------------------------------------------------------------------------
// Prep: fp32 weights -> bf16 fragment-major in d_ws; biases bb = bih + bhh.
// ---------------------------------------------------------------------------
__global__ void actp_prep(
    const float* __restrict__ Wih1, const float* __restrict__ Whh1,
    const float* __restrict__ bih1, const float* __restrict__ bhh1,
    const float* __restrict__ Wih2, const float* __restrict__ Whh2,
    const float* __restrict__ bih2, const float* __restrict__ bhh2,
    const float* __restrict__ W1,   const float* __restrict__ W2,
    unsigned short* __restrict__ ws)
{
  const int bid = blockIdx.x, l = threadIdx.x;
  if (bid >= NFRAG) {                      // bias blocks
    const int idx = (bid - NFRAG) * 64 + l;
    float* bb = (float*)(ws + (size_t)NFRAG * 512);   // bytes NFRAG*1024
    if (idx < 800)        bb[idx] = bih1[idx] + bhh1[idx];
    else if (idx < 1600)  bb[idx] = bih2[idx - 800] + bhh2[idx - 800];
    return;
  }
  const int ncol = l & 31;
  const int kb   = (l >> 5) * 8;
  float v[8];
  if (bid < FRAG_B2) {                     // lstm1: K = [x1(48) | h1(208 pad)]
    int t = bid; const int g = t / 112; t -= g * 112;
    const int jt = t / 16, kc = t % 16;
    const int n = jt * 32 + ncol, row = g * 200 + n;
#pragma unroll
    for (int i = 0; i < 8; ++i) {
      const int k = kc * 16 + kb + i; float val = 0.f;
      if (n < 200) {
        if (kc < 3) val = Wih1[row * 48 + k];
        else { const int kk = k - 48; if (kk < 200) val = Whh1[row * 200 + kk]; }
      }
      v[i] = val;
    }
  } else if (bid < FRAG_BF1) {             // lstm2: K = [h1 208 | tiled 48 | h2 208]
    int t = bid - FRAG_B2; const int g = t / 203; t -= g * 203;
    const int jt = t / 29, kc = t % 29;
    const int n = jt * 32 + ncol, row = g * 200 + n;
#pragma unroll
    for (int i = 0; i < 8; ++i) {
      const int k = kc * 16 + kb + i; float val = 0.f;
      if (n < 200) {
        if (kc < 13)      { if (k < 200) val = Wih2[row * 248 + k]; }
        else if (kc < 16) { val = Wih2[row * 248 + 200 + (k - 208)]; }
        else { const int kk = k - 256; if (kk < 200) val = Whh2[row * 200 + kk]; }
      }
      v[i] = val;
    }
  } else if (bid < FRAG_BF2) {             // fc1: K = [h2 208 | x1 48]
    int t = bid - FRAG_BF1; const int jt = t / 16, kc = t % 16;
    const int n = jt * 32 + ncol;
#pragma unroll
    for (int i = 0; i < 8; ++i) {
      const int k = kc * 16 + kb + i; float val = 0.f;
      if (n < 200) {
        if (kc < 13) { if (k < 200) val = W1[n * 248 + k]; }
        else         val = W1[n * 248 + 200 + (k - 208)];
      }
      v[i] = val;
    }
  } else {                                 // fc2: K = out3(208 pad), N 48->64
    int t = bid - FRAG_BF2; const int jt = t / 13, kc = t % 13;
    const int n = jt * 32 + ncol;
#pragma unroll
    for (int i = 0; i < 8; ++i) {
      const int k = kc * 16 + kb + i; float val = 0.f;
      if (n < 48 && k < 200) val = W2[n * 200 + k];
      v[i] = val;
    }
  }
  bf16x8 o;
#pragma unroll
  for (int i = 0; i < 8; ++i) o[i] = (short)f2bf(v[i]);
  ((bf16x8*)ws)[(size_t)bid * 64 + l] = o;
}

// ---------------------------------------------------------------------------
// Dual-row-tile single-gate GEMM. A from LDS (up to 3 segments, tile t adds
// t*32 rows), B from global fragment-major (SGPR-uniform base), SHARED by
// both row-tiles: one b-frag feeds two MFMAs. acc[2] init'd inside.
// a0/a1 2-deep, b 8-deep prefetch; all rotating indices compile-time.
// ---------------------------------------------------------------------------
template<int KC, int C1, int C2>
__device__ __forceinline__ void gemm2m(
    const unsigned short* __restrict__ A1, int S1,
    const unsigned short* __restrict__ A2, int S2,
    const unsigned short* __restrict__ A3, int S3,
    const bf16x8* __restrict__ B, f32x16* acc, int lane)
{
  const int r32 = lane & 31, ao = (lane >> 5) * 8;
#define APTR(kc, t) ((kc) < C1 ? (A1 + ((t) * 32 + r32) * S1 + (kc) * 16 + ao) \
               : ((kc) < C2 ? (A2 + ((t) * 32 + r32) * S2 + ((kc) - C1) * 16 + ao) \
                            : (A3 + ((t) * 32 + r32) * S3 + ((kc) - C2) * 16 + ao)))
#pragma unroll
  for (int r = 0; r < 16; ++r) { acc[0][r] = 0.f; acc[1][r] = 0.f; }
  bf16x8 a0[2], a1[2];
  a0[0] = *(const bf16x8*)APTR(0, 0);
  a1[0] = *(const bf16x8*)APTR(0, 1);
  if (KC > 1) {
    a0[1] = *(const bf16x8*)APTR(1, 0);
    a1[1] = *(const bf16x8*)APTR(1, 1);
  }
  bf16x8 b[8];
#pragma unroll
  for (int p = 0; p < 8 && p < KC; ++p) b[p] = B[(size_t)p * 64 + lane];
#pragma unroll
  for (int kc = 0; kc < KC; ++kc) {
    acc[0] = __builtin_amdgcn_mfma_f32_32x32x16_bf16(a0[kc & 1], b[kc & 7], acc[0], 0, 0, 0);
    acc[1] = __builtin_amdgcn_mfma_f32_32x32x16_bf16(a1[kc & 1], b[kc & 7], acc[1], 0, 0, 0);
    if (kc + 2 < KC) {
      a0[kc & 1] = *(const bf16x8*)APTR(kc + 2, 0);
      a1[kc & 1] = *(const bf16x8*)APTR(kc + 2, 1);
    }
    if (kc + 8 < KC) b[kc & 7] = B[(size_t)(kc + 8) * 64 + lane];
  }
#undef APTR
}

// ---------------------------------------------------------------------------
// Main persistent kernel: 512 blocks x 512 threads (8 waves), 64 batch rows
// per block (two 32-row tiles per wave). 128KB dynamic LDS.
// amdgpu_num_vgpr(224): explicit register budget (occupancy is LDS-pinned at
// 2 waves/SIMD anyway; the allocator's 128 heuristic just causes spill).
// ---------------------------------------------------------------------------
__global__ __launch_bounds__(512)
__attribute__((amdgpu_num_vgpr(224)))
void actp_main(
    const float* __restrict__ tact, const float* __restrict__ act,
    const unsigned short* __restrict__ ws,
    const float* __restrict__ b1v, const float* __restrict__ b2v,
    float* __restrict__ out)
{
  extern __shared__ unsigned short lds[];            // 128KB dynamic
  unsigned short* const h1bufA = lds;                // 64*232 = 14848 ush each
  unsigned short* const h1bufB = lds + 14848;
  unsigned short* const h2bufA = lds + 29696;
  unsigned short* const h2bufB = lds + 44544;
  unsigned short* const x1b    = lds + 59392;        // 64*48 = 3072
  unsigned short* const tld    = lds + 62464;        // 64*48  (end 65536 ush = 128KB)

  const int tid = threadIdx.x, lane = tid & 63, wid = tid >> 6;
  const int q = wid;                                  // gate-col tile; q==7 idle
  const int l31 = lane & 31, kh = lane >> 5;
  const int jc = q * 32 + l31;                        // output column
  const size_t rowbase = (size_t)blockIdx.x * 64;

  const float* const bb1 = (const float*)(ws + (size_t)NFRAG * 512);
  const float* const bb2 = bb1 + 800;
  const bool vv = jc < 200;

  // zero-init the "old" parity state buffers (h(-1) = 0); 7424 uints each
  for (int i = tid; i < 7424; i += 512) {
    ((unsigned int*)h1bufB)[i] = 0u;
    ((unsigned int*)h2bufB)[i] = 0u;
  }

  float c1[2][16], c2[2][16], tmp[2][16];
#pragma unroll
  for (int t = 0; t < 2; ++t)
#pragma unroll
    for (int r = 0; r < 16; ++r) { c1[t][r] = 0.f; c2[t][r] = 0.f; }

  for (int s = 0; s < 19; ++s) {
    // ---- stage x1 = tactiles[s] (context steps only; pred steps keep out4) --
    if (s < 10 && tid < 384) {
      const int row = tid / 6, ch = tid % 6;
      const float* src = tact + ((size_t)s * 32768 + rowbase + row) * 48 + ch * 8;
      float4 v0 = *(const float4*)src;
      float4 v1 = *(const float4*)(src + 4);
      bf16x8 u;
      u[0] = (short)f2bf(v0.x); u[1] = (short)f2bf(v0.y);
      u[2] = (short)f2bf(v0.z); u[3] = (short)f2bf(v0.w);
      u[4] = (short)f2bf(v1.x); u[5] = (short)f2bf(v1.y);
      u[6] = (short)f2bf(v1.z); u[7] = (short)f2bf(v1.w);
      *(bf16x8*)(x1b + row * 48 + ch * 8) = u;
    }
    // ---- stage tiled(act=actions[s+1], state=actions[0]) -------------------
    if (tid < 128) {
      const int row = tid >> 1, hf = tid & 1;
      const float* pa = act + ((size_t)(s + 1) * 32768 + rowbase + row) * 6;
      const float* ps = act + (rowbase + row) * 6;
      float a6[6], s6[6];
#pragma unroll
      for (int j = 0; j < 6; ++j) { a6[j] = pa[j]; s6[j] = ps[j]; }
#pragma unroll
      for (int k = 0; k < 3; ++k) {
        bf16x8 w;
#pragma unroll
        for (int j = 0; j < 8; ++j) {
          const int c = k * 8 + j;          // local col 0..23; global parity = (c/6)&1
          const int b6 = c / 6, jj = c % 6;
          w[j] = (short)f2bf((b6 & 1) ? s6[jj] : a6[jj]);
        }
        *(bf16x8*)(tld + row * 48 + hf * 24 + k * 8) = w;
      }
    }
    __syncthreads();

    const int P = s & 1;
    unsigned short* const h1n = P ? h1bufB : h1bufA;
    unsigned short* const h1o = P ? h1bufA : h1bufB;
    unsigned short* const h2n = P ? h2bufB : h2bufA;
    unsigned short* const h2o = P ? h2bufA : h2bufB;

    // ================= LSTM1: z = [x1 | h1_old] @ W^T + bb1 =================
    // 4 single-gate passes, order f -> i -> g -> o; two row-tiles per pass.
    if (q < 7) {
      f32x16 z[2];
      {  // f: c1 *= sig(f)
        const float bf = vv ? bb1[200 + jc] : 0.f;
        gemm2m<16, 3, 16>(x1b, 48, h1o, 232, h1o, 232,
                          uni_frag(ws, 112 + q * 16), z, lane);
#pragma unroll
        for (int t = 0; t < 2; ++t)
#pragma unroll
          for (int r = 0; r < 16; ++r) c1[t][r] *= sigf(z[t][r] + bf);
      }
      {  // i: tmp = sig(i)
        const float bi = vv ? bb1[jc] : 0.f;
        gemm2m<16, 3, 16>(x1b, 48, h1o, 232, h1o, 232,
                          uni_frag(ws, q * 16), z, lane);
#pragma unroll
        for (int t = 0; t < 2; ++t)
#pragma unroll
          for (int r = 0; r < 16; ++r) tmp[t][r] = sigf(z[t][r] + bi);
      }
      {  // g: c1 += tmp * tanh(g)
        const float bg = vv ? bb1[400 + jc] : 0.f;
        gemm2m<16, 3, 16>(x1b, 48, h1o, 232, h1o, 232,
                          uni_frag(ws, 224 + q * 16), z, lane);
#pragma unroll
        for (int t = 0; t < 2; ++t)
#pragma unroll
          for (int r = 0; r < 16; ++r) c1[t][r] += tmp[t][r] * tanh_f(z[t][r] + bg);
      }
      {  // o: h1 = sig(o) * tanh(c1)
        const float bo = vv ? bb1[600 + jc] : 0.f;
        gemm2m<16, 3, 16>(x1b, 48, h1o, 232, h1o, 232,
                          uni_frag(ws, 336 + q * 16), z, lane);
#pragma unroll
        for (int t = 0; t < 2; ++t)
#pragma unroll
          for (int r = 0; r < 16; ++r) {
            const int row = t * 32 + 4 * kh + 8 * (r >> 2) + (r & 3);
            h1n[row * 232 + jc] = f2bf(sigf(z[t][r] + bo) * tanh_f(c1[t][r]));
          }
      }
    }
    __syncthreads();

    // ============ LSTM2: z = [h1_new | tiled | h2_old] @ W^T + bb2 ==========
    if (q < 7) {
      f32x16 z[2];
      {  // f
        const float bf = vv ? bb2[200 + jc] : 0.f;
        gemm2m<29, 13, 16>(h1n, 232, tld, 48, h2o, 232,
                           uni_frag(ws, FRAG_B2 + 203 + q * 29), z, lane);
#pragma unroll
        for (int t = 0; t < 2; ++t)
#pragma unroll
          for (int r = 0; r < 16; ++r) c2[t][r] *= sigf(z[t][r] + bf);
      }
      {  // i
        const float bi = vv ? bb2[jc] : 0.f;
        gemm2m<29, 13, 16>(h1n, 232, tld, 48, h2o, 232,
                           uni_frag(ws, FRAG_B2 + q * 29), z, lane);
#pragma unroll
        for (int t = 0; t < 2; ++t)
#pragma unroll
          for (int r = 0; r < 16; ++r) tmp[t][r] = sigf(z[t][r] + bi);
      }
      {  // g
        const float bg = vv ? bb2[400 + jc] : 0.f;
        gemm2m<29, 13, 16>(h1n, 232, tld, 48, h2o, 232,
                           uni_frag(ws, FRAG_B2 + 406 + q * 29), z, lane);
#pragma unroll
        for (int t = 0; t < 2; ++t)
#pragma unroll
          for (int r = 0; r < 16; ++r) c2[t][r] += tmp[t][r] * tanh_f(z[t][r] + bg);
      }
      {  // o
        const float bo = vv ? bb2[600 + jc] : 0.f;
        gemm2m<29, 13, 16>(h1n, 232, tld, 48, h2o, 232,
                           uni_frag(ws, FRAG_B2 + 609 + q * 29), z, lane);
#pragma unroll
        for (int t = 0; t < 2; ++t)
#pragma unroll
          for (int r = 0; r < 16; ++r) {
            const int row = t * 32 + 4 * kh + 8 * (r >> 2) + (r & 3);
            h2n[row * 232 + jc] = f2bf(sigf(z[t][r] + bo) * tanh_f(c2[t][r]));
          }
      }
    }
    __syncthreads();

    // ================= FC1 / FC2 (only for steps that emit output) ==========
    if (s >= 9) {
      unsigned short* const o3 = h1o;   // alias dead h1-old buffer, stride 232
      if (wid < 7) {
        f32x16 a[2];
        const float br = vv ? b1v[jc] : 0.f;
        gemm2m<16, 13, 16>(h2n, 232, x1b, 48, x1b, 48,
                           uni_frag(ws, FRAG_BF1 + wid * 16), a, lane);
#pragma unroll
        for (int t = 0; t < 2; ++t)
#pragma unroll
          for (int r = 0; r < 16; ++r) {
            const int row = t * 32 + 4 * kh + 8 * (r >> 2) + (r & 3);
            o3[row * 232 + jc] = f2bf(tanh_f(a[t][r] + br));
          }
      }
      __syncthreads();
      if (wid < 2) {
        f32x16 a[2];
        const float br = (jc < 48) ? b2v[jc] : 0.f;
        gemm2m<13, 13, 13>(o3, 232, o3, 232, o3, 232,
                           uni_frag(ws, FRAG_BF2 + wid * 13), a, lane);
        if (jc < 48) {
#pragma unroll
          for (int t = 0; t < 2; ++t)
#pragma unroll
            for (int r = 0; r < 16; ++r) {
              const int row = t * 32 + 4 * kh + 8 * (r >> 2) + (r & 3);
              const float v = tanh_f(a[t][r] + br);
              out[((size_t)(s - 9) * 32768 + rowbase + row) * 48 + jc] = v;
              x1b[row * 48 + jc] = f2bf(v);    // out4 -> x1 for next (pred) step
            }
        }
      }
      __syncthreads();
    }
  }
}

// ---------------------------------------------------------------------------
extern "C" void kernel_launch(void* const* d_in, const int* in_sizes, int n_in,
                              void* d_out, int out_size, void* d_ws, size_t ws_size,
                              hipStream_t stream) {
  const float* tactp = (const float*)d_in[0];
  const float* actp  = (const float*)d_in[1];
  const float* Wih1  = (const float*)d_in[2];
  const float* Whh1  = (const float*)d_in[3];
  const float* bih1  = (const float*)d_in[4];
  const float* bhh1  = (const float*)d_in[5];
  const float* Wih2  = (const float*)d_in[6];
  const float* Whh2  = (const float*)d_in[7];
  const float* bih2  = (const float*)d_in[8];
  const float* bhh2  = (const float*)d_in[9];
  const float* W1    = (const float*)d_in[10];
  const float* b1    = (const float*)d_in[11];
  const float* W2    = (const float*)d_in[12];
  const float* b2    = (const float*)d_in[13];
  unsigned short* ws = (unsigned short*)d_ws;
  float* outp = (float*)d_out;

  hipFuncSetAttribute((const void*)actp_main,
                      hipFuncAttributeMaxDynamicSharedMemorySize, 131072);

  actp_prep<<<NFRAG + 25, 64, 0, stream>>>(Wih1, Whh1, bih1, bhh1,
                                           Wih2, Whh2, bih2, bhh2, W1, W2, ws);
  actp_main<<<512, 512, 131072, stream>>>(tactp, actp, ws, b1, b2, outp);
}

// Round 10
// 2291.004 us; speedup vs baseline: 1.3343x; 1.3343x over previous
//
#include <hip/hip_runtime.h>

// ============================================================================
// ACTP two-layer LSTM rollout, persistent-kernel bf16-MFMA implementation.
//
// R15 = R14 resubmitted verbatim (R14's bench was an infrastructure failure:
// "MI355X container failed twice" — kernel never executed).
//
// R14 change: revert to R11 (best, 1537us) + two-gate passes sharing one
// LDS A-stream.
//   Evidence: R13's amdgpu_num_vgpr(224) was IGNORED (VGPR_Count 128,
//   counters identical to R12) -> 128 arch + ~128 AGPR is the allocator's
//   hard operating point; M=64 line dead. R11 issue-level model: per kc,
//   1 MFMA (8cy) + 1 ds_read_b128 (~12cy) + 1 B-load; per KC=16 pass the
//   ds_read stream (192cy) exceeds MFMA (128cy) -> LDS A-reads co-limit.
//   Fits counters: MfmaUtil 24.5 < VALUBusy 30, both far from cap.
//   Fix: A fragments are IDENTICAL for all 4 gates -> 2 gates/pass share
//   one A stream (R5/R6 structure, now viable since R9's uni_frag removed
//   the divergent-pointer spill that sank it). ds_reads/cell halve
//   (lstm1 64->32, lstm2 116->58); pass drains halve; MFMA unchanged.
//   Worst-pass arch live ~102 nominal (c1 16 + c2 16 + tmp 16 + b 32 +
//   a 8 + bias 2 + addr) + temps ~= 130. WRITE_SIZE is the dosimeter:
//   >300MB means overflow -> shrink B-depth or revert.
//
// Structure:
//  - 1024 blocks x 512 threads (8 waves), 32 batch rows/block, 19 steps.
//  - Wave q=wid: gate-col-tile jt=q (q==7 idle in LSTM gemms). 2 two-gate
//    passes per cell: (f,i) then (g,o); tmp=sig(i) carried across one
//    boundary; two f32x16 AGPR accumulators per pass; a[2] + bx[4]/by[4]
//    prefetch (8 outstanding B loads, same as R11); B bases scalarized
//    via readfirstlane (uni_frag).
//  - h1/h2 double-buffered in LDS bf16 (32 rows x stride 232), 64KB static.
//    fc1 "out3" aliases dead h1-old.
//  - Weights pre-converted to bf16 fragment-major (frag = 64 lanes x 16B,
//    coalesced 1KB loads), N padded 200->224 (7 jt of 32), K chunks of 16.
//  - fc1/fc2 (gemm1g, single stream) skipped for context steps 0..8.
// MFMA v_mfma_f32_32x32x16_bf16 layouts (per cdna4_isa.md):
//   A: m=lane&31, k=8*(lane>>5)+i ; B: n=lane&31, k=8*(lane>>5)+i
//   C/D: col=lane&31, row=(r&3)+8*(r>>2)+4*(lane>>5)
// ============================================================================

typedef short bf16x8 __attribute__((ext_vector_type(8)));
typedef float f32x16 __attribute__((ext_vector_type(16)));

#define NFRAG    1398
#define FRAG_B2  448     // lstm1: 4*7*16 frags
#define FRAG_BF1 1260    // lstm2: 4*7*29 frags
#define FRAG_BF2 1372    // fc1:   7*16 frags ; fc2: 2*13 frags

__device__ __forceinline__ unsigned short f2bf(float f) {
  unsigned int x = __float_as_uint(f);
  x += 0x7fffu + ((x >> 16) & 1u);          // RNE; inputs are finite
  return (unsigned short)(x >> 16);
}
__device__ __forceinline__ float sigf(float x) {
  return __builtin_amdgcn_rcpf(1.f + __expf(-x));   // exp(inf)->inf->rcp->0: safe
}
__device__ __forceinline__ float tanh_f(float x) {
  float e = __expf(2.f * fabsf(x));                 // e>=1, inf handled (t->1)
  float t = 1.f - 2.f * __builtin_amdgcn_rcpf(e + 1.f);
  return copysignf(t, x);
}

// Force a wave-uniform fragment index into an SGPR and build the stream base.
// frag is uniform within the wave (derived from wid), so readfirstlane is
// exact; the resulting pointer is SGPR-held, not a per-lane VGPR pair.
__device__ __forceinline__ const bf16x8* uni_frag(
    const unsigned short* __restrict__ ws, int frag) {
  const int f = __builtin_amdgcn_readfirstlane(frag);
  return (const bf16x8*)(ws + (size_t)f * 512);     // 512 ushort = 1KB/frag
}

// ---------------------------------------------------------------------------
// Prep: fp32 weights -> bf16 fragment-major in d_ws; biases bb = bih + bhh.
// ---------------------------------------------------------------------------
__global__ void actp_prep(
    const float* __restrict__ Wih1, const float* __restrict__ Whh1,
    const float* __restrict__ bih1, const float* __restrict__ bhh1,
    const float* __restrict__ Wih2, const float* __restrict__ Whh2,
    const float* __restrict__ bih2, const float* __restrict__ bhh2,
    const float* __restrict__ W1,   const float* __restrict__ W2,
    unsigned short* __restrict__ ws)
{
  const int bid = blockIdx.x, l = threadIdx.x;
  if (bid >= NFRAG) {                      // bias blocks
    const int idx = (bid - NFRAG) * 64 + l;
    float* bb = (float*)(ws + (size_t)NFRAG * 512);   // bytes NFRAG*1024
    if (idx < 800)        bb[idx] = bih1[idx] + bhh1[idx];
    else if (idx < 1600)  bb[idx] = bih2[idx - 800] + bhh2[idx - 800];
    return;
  }
  const int ncol = l & 31;
  const int kb   = (l >> 5) * 8;
  float v[8];
  if (bid < FRAG_B2) {                     // lstm1: K = [x1(48) | h1(208 pad)]
    int t = bid; const int g = t / 112; t -= g * 112;
    const int jt = t / 16, kc = t % 16;
    const int n = jt * 32 + ncol, row = g * 200 + n;
#pragma unroll
    for (int i = 0; i < 8; ++i) {
      const int k = kc * 16 + kb + i; float val = 0.f;
      if (n < 200) {
        if (kc < 3) val = Wih1[row * 48 + k];
        else { const int kk = k - 48; if (kk < 200) val = Whh1[row * 200 + kk]; }
      }
      v[i] = val;
    }
  } else if (bid < FRAG_BF1) {             // lstm2: K = [h1 208 | tiled 48 | h2 208]
    int t = bid - FRAG_B2; const int g = t / 203; t -= g * 203;
    const int jt = t / 29, kc = t % 29;
    const int n = jt * 32 + ncol, row = g * 200 + n;
#pragma unroll
    for (int i = 0; i < 8; ++i) {
      const int k = kc * 16 + kb + i; float val = 0.f;
      if (n < 200) {
        if (kc < 13)      { if (k < 200) val = Wih2[row * 248 + k]; }
        else if (kc < 16) { val = Wih2[row * 248 + 200 + (k - 208)]; }
        else { const int kk = k - 256; if (kk < 200) val = Whh2[row * 200 + kk]; }
      }
      v[i] = val;
    }
  } else if (bid < FRAG_BF2) {             // fc1: K = [h2 208 | x1 48]
    int t = bid - FRAG_BF1; const int jt = t / 16, kc = t % 16;
    const int n = jt * 32 + ncol;
#pragma unroll
    for (int i = 0; i < 8; ++i) {
      const int k = kc * 16 + kb + i; float val = 0.f;
      if (n < 200) {
        if (kc < 13) { if (k < 200) val = W1[n * 248 + k]; }
        else         val = W1[n * 248 + 200 + (k - 208)];
      }
      v[i] = val;
    }
  } else {                                 // fc2: K = out3(208 pad), N 48->64
    int t = bid - FRAG_BF2; const int jt = t / 13, kc = t % 13;
    const int n = jt * 32 + ncol;
#pragma unroll
    for (int i = 0; i < 8; ++i) {
      const int k = kc * 16 + kb + i; float val = 0.f;
      if (n < 48 && k < 200) val = W2[n * 200 + k];
      v[i] = val;
    }
  }
  bf16x8 o;
#pragma unroll
  for (int i = 0; i < 8; ++i) o[i] = (short)f2bf(v[i]);
  ((bf16x8*)ws)[(size_t)bid * 64 + l] = o;
}

// ---------------------------------------------------------------------------
// Two-gate GEMM: ONE shared A-stream (LDS, up to 3 segments), TWO B streams
// (global fragment-major, SGPR-uniform bases), two f32x16 AGPR accumulators.
// a[2] + bx[4]/by[4] prefetch (8 outstanding B); indices compile-time.
// ---------------------------------------------------------------------------
template<int KC, int C1, int C2>
__device__ __forceinline__ void gemm2g(
    const unsigned short* __restrict__ A1, int S1,
    const unsigned short* __restrict__ A2, int S2,
    const unsigned short* __restrict__ A3, int S3,
    const bf16x8* __restrict__ Bx, const bf16x8* __restrict__ By,
    f32x16* acc, int lane)
{
  const int r32 = lane & 31, ao = (lane >> 5) * 8;
#define APTR(kc) ((kc) < C1 ? (A1 + r32 * S1 + (kc) * 16 + ao) \
               : ((kc) < C2 ? (A2 + r32 * S2 + ((kc) - C1) * 16 + ao) \
                            : (A3 + r32 * S3 + ((kc) - C2) * 16 + ao)))
#pragma unroll
  for (int r = 0; r < 16; ++r) { acc[0][r] = 0.f; acc[1][r] = 0.f; }
  bf16x8 a[2];
  a[0] = *(const bf16x8*)APTR(0);
  if (KC > 1) a[1] = *(const bf16x8*)APTR(1);
  bf16x8 bx[4], by[4];
#pragma unroll
  for (int p = 0; p < 4 && p < KC; ++p) {
    bx[p] = Bx[(size_t)p * 64 + lane];
    by[p] = By[(size_t)p * 64 + lane];
  }
#pragma unroll
  for (int kc = 0; kc < KC; ++kc) {
    acc[0] = __builtin_amdgcn_mfma_f32_32x32x16_bf16(a[kc & 1], bx[kc & 3], acc[0], 0, 0, 0);
    acc[1] = __builtin_amdgcn_mfma_f32_32x32x16_bf16(a[kc & 1], by[kc & 3], acc[1], 0, 0, 0);
    if (kc + 2 < KC) a[kc & 1] = *(const bf16x8*)APTR(kc + 2);
    if (kc + 4 < KC) {
      bx[kc & 3] = Bx[(size_t)(kc + 4) * 64 + lane];
      by[kc & 3] = By[(size_t)(kc + 4) * 64 + lane];
    }
  }
#undef APTR
}

// ---------------------------------------------------------------------------
// Single-stream GEMM (fc1/fc2). A from LDS, B global (SGPR-uniform base).
// a[4]/b[8] prefetch as in R11.
// ---------------------------------------------------------------------------
template<int KC, int C1, int C2>
__device__ __forceinline__ f32x16 gemm1g(
    const unsigned short* __restrict__ A1, int S1,
    const unsigned short* __restrict__ A2, int S2,
    const unsigned short* __restrict__ A3, int S3,
    const bf16x8* __restrict__ B, int lane)
{
  const int r32 = lane & 31, ao = (lane >> 5) * 8;
#define APTR1(kc) ((kc) < C1 ? (A1 + r32 * S1 + (kc) * 16 + ao) \
               : ((kc) < C2 ? (A2 + r32 * S2 + ((kc) - C1) * 16 + ao) \
                            : (A3 + r32 * S3 + ((kc) - C2) * 16 + ao)))
  f32x16 acc;
#pragma unroll
  for (int r = 0; r < 16; ++r) acc[r] = 0.f;
  bf16x8 a[4];
#pragma unroll
  for (int p = 0; p < 4 && p < KC; ++p) a[p] = *(const bf16x8*)APTR1(p);
  bf16x8 b[8];
#pragma unroll
  for (int p = 0; p < 8 && p < KC; ++p) b[p] = B[(size_t)p * 64 + lane];
#pragma unroll
  for (int kc = 0; kc < KC; ++kc) {
    acc = __builtin_amdgcn_mfma_f32_32x32x16_bf16(a[kc & 3], b[kc & 7], acc, 0, 0, 0);
    if (kc + 4 < KC) a[kc & 3] = *(const bf16x8*)APTR1(kc + 4);
    if (kc + 8 < KC) b[kc & 7] = B[(size_t)(kc + 8) * 64 + lane];
  }
#undef APTR1
  return acc;
}

// ---------------------------------------------------------------------------
// Main persistent kernel: 1024 blocks x 512 threads (8 waves), 32 batch rows
// per block. Static 64KB LDS; waves_per_eu(2).
// ---------------------------------------------------------------------------
__global__ __launch_bounds__(512)
__attribute__((amdgpu_waves_per_eu(2)))
void actp_main(
    const float* __restrict__ tact, const float* __restrict__ act,
    const unsigned short* __restrict__ ws,
    const float* __restrict__ b1v, const float* __restrict__ b2v,
    float* __restrict__ out)
{
  __shared__ unsigned short lds[32768];              // 64KB static
  unsigned short* const h1bufA = lds;                // 32*232 = 7424 ush each
  unsigned short* const h1bufB = lds + 7424;
  unsigned short* const h2bufA = lds + 14848;
  unsigned short* const h2bufB = lds + 22272;
  unsigned short* const x1b    = lds + 29696;        // 32*48
  unsigned short* const tld    = lds + 31232;        // 32*48  (end 32768 ush = 64KB)

  const int tid = threadIdx.x, lane = tid & 63, wid = tid >> 6;
  const int q = wid;                                  // gate-col tile; q==7 idle
  const int l31 = lane & 31, kh = lane >> 5;
  const int jc = q * 32 + l31;                        // output column
  const size_t rowbase = (size_t)blockIdx.x * 32;

  const float* const bb1 = (const float*)(ws + (size_t)NFRAG * 512);
  const float* const bb2 = bb1 + 800;
  const bool vv = jc < 200;

  // zero-init the "old" parity state buffers (h(-1) = 0)
  for (int i = tid; i < 3712; i += 512) {
    ((unsigned int*)h1bufB)[i] = 0u;
    ((unsigned int*)h2bufB)[i] = 0u;
  }

  float c1[16], c2[16], tmp[16];
#pragma unroll
  for (int r = 0; r < 16; ++r) { c1[r] = 0.f; c2[r] = 0.f; }

  for (int s = 0; s < 19; ++s) {
    // ---- stage x1 = tactiles[s] (context steps only; pred steps keep out4) --
    if (s < 10 && tid < 192) {
      const int row = tid / 6, ch = tid % 6;
      const float* src = tact + ((size_t)s * 32768 + rowbase + row) * 48 + ch * 8;
      float4 v0 = *(const float4*)src;
      float4 v1 = *(const float4*)(src + 4);
      bf16x8 u;
      u[0] = (short)f2bf(v0.x); u[1] = (short)f2bf(v0.y);
      u[2] = (short)f2bf(v0.z); u[3] = (short)f2bf(v0.w);
      u[4] = (short)f2bf(v1.x); u[5] = (short)f2bf(v1.y);
      u[6] = (short)f2bf(v1.z); u[7] = (short)f2bf(v1.w);
      *(bf16x8*)(x1b + row * 48 + ch * 8) = u;
    }
    // ---- stage tiled(act=actions[s+1], state=actions[0]) -------------------
    if (tid < 64) {
      const int row = tid >> 1, hf = tid & 1;
      const float* pa = act + ((size_t)(s + 1) * 32768 + rowbase + row) * 6;
      const float* ps = act + (rowbase + row) * 6;
      float a6[6], s6[6];
#pragma unroll
      for (int j = 0; j < 6; ++j) { a6[j] = pa[j]; s6[j] = ps[j]; }
#pragma unroll
      for (int k = 0; k < 3; ++k) {
        bf16x8 w;
#pragma unroll
        for (int j = 0; j < 8; ++j) {
          const int c = k * 8 + j;          // local col 0..23; global parity = (c/6)&1
          const int b6 = c / 6, jj = c % 6;
          w[j] = (short)f2bf((b6 & 1) ? s6[jj] : a6[jj]);
        }
        *(bf16x8*)(tld + row * 48 + hf * 24 + k * 8) = w;
      }
    }
    __syncthreads();

    const int P = s & 1;
    unsigned short* const h1n = P ? h1bufB : h1bufA;
    unsigned short* const h1o = P ? h1bufA : h1bufB;
    unsigned short* const h2n = P ? h2bufB : h2bufA;
    unsigned short* const h2o = P ? h2bufA : h2bufB;

    // ================= LSTM1: z = [x1 | h1_old] @ W^T + bb1 =================
    // 2 two-gate passes: (f,i) then (g,o). One shared A-stream per pass.
    if (q < 7) {
      f32x16 z[2];
      {  // (f,i): c1 *= sig(f); tmp = sig(i)
        const float bf = vv ? bb1[200 + jc] : 0.f;
        const float bi = vv ? bb1[jc] : 0.f;
        gemm2g<16, 3, 16>(x1b, 48, h1o, 232, h1o, 232,
                          uni_frag(ws, 112 + q * 16),
                          uni_frag(ws, q * 16), z, lane);
#pragma unroll
        for (int r = 0; r < 16; ++r) {
          c1[r] *= sigf(z[0][r] + bf);
          tmp[r] = sigf(z[1][r] + bi);
        }
      }
      {  // (g,o): c1 += tmp*tanh(g); h1 = sig(o)*tanh(c1)
        const float bg = vv ? bb1[400 + jc] : 0.f;
        const float bo = vv ? bb1[600 + jc] : 0.f;
        gemm2g<16, 3, 16>(x1b, 48, h1o, 232, h1o, 232,
                          uni_frag(ws, 224 + q * 16),
                          uni_frag(ws, 336 + q * 16), z, lane);
#pragma unroll
        for (int r = 0; r < 16; ++r) {
          c1[r] += tmp[r] * tanh_f(z[0][r] + bg);
          const int row = 4 * kh + 8 * (r >> 2) + (r & 3);
          h1n[row * 232 + jc] = f2bf(sigf(z[1][r] + bo) * tanh_f(c1[r]));
        }
      }
    }
    __syncthreads();

    // ============ LSTM2: z = [h1_new | tiled | h2_old] @ W^T + bb2 ==========
    if (q < 7) {
      f32x16 z[2];
      {  // (f,i)
        const float bf = vv ? bb2[200 + jc] : 0.f;
        const float bi = vv ? bb2[jc] : 0.f;
        gemm2g<29, 13, 16>(h1n, 232, tld, 48, h2o, 232,
                           uni_frag(ws, FRAG_B2 + 203 + q * 29),
                           uni_frag(ws, FRAG_B2 + q * 29), z, lane);
#pragma unroll
        for (int r = 0; r < 16; ++r) {
          c2[r] *= sigf(z[0][r] + bf);
          tmp[r] = sigf(z[1][r] + bi);
        }
      }
      {  // (g,o)
        const float bg = vv ? bb2[400 + jc] : 0.f;
        const float bo = vv ? bb2[600 + jc] : 0.f;
        gemm2g<29, 13, 16>(h1n, 232, tld, 48, h2o, 232,
                           uni_frag(ws, FRAG_B2 + 406 + q * 29),
                           uni_frag(ws, FRAG_B2 + 609 + q * 29), z, lane);
#pragma unroll
        for (int r = 0; r < 16; ++r) {
          c2[r] += tmp[r] * tanh_f(z[0][r] + bg);
          const int row = 4 * kh + 8 * (r >> 2) + (r & 3);
          h2n[row * 232 + jc] = f2bf(sigf(z[1][r] + bo) * tanh_f(c2[r]));
        }
      }
    }
    __syncthreads();

    // ================= FC1 / FC2 (only for steps that emit output) ==========
    if (s >= 9) {
      unsigned short* const o3 = h1o;   // alias dead h1-old buffer, stride 232
      if (wid < 7) {
        const float br = vv ? b1v[jc] : 0.f;
        f32x16 a = gemm1g<16, 13, 16>(h2n, 232, x1b, 48, x1b, 48,
                                      uni_frag(ws, FRAG_BF1 + wid * 16), lane);
#pragma unroll
        for (int r = 0; r < 16; ++r) {
          const int row = 4 * kh + 8 * (r >> 2) + (r & 3);
          o3[row * 232 + jc] = f2bf(tanh_f(a[r] + br));
        }
      }
      __syncthreads();
      if (wid < 2) {
        const float br = (jc < 48) ? b2v[jc] : 0.f;
        f32x16 a = gemm1g<13, 13, 13>(o3, 232, o3, 232, o3, 232,
                                      uni_frag(ws, FRAG_BF2 + wid * 13), lane);
        if (jc < 48) {
#pragma unroll
          for (int r = 0; r < 16; ++r) {
            const int row = 4 * kh + 8 * (r >> 2) + (r & 3);
            const float v = tanh_f(a[r] + br);
            out[((size_t)(s - 9) * 32768 + rowbase + row) * 48 + jc] = v;
            x1b[row * 48 + jc] = f2bf(v);    // out4 -> x1 for next (pred) step
          }
        }
      }
      __syncthreads();
    }
  }
}

// ---------------------------------------------------------------------------
extern "C" void kernel_launch(void* const* d_in, const int* in_sizes, int n_in,
                              void* d_out, int out_size, void* d_ws, size_t ws_size,
                              hipStream_t stream) {
  const float* tactp = (const float*)d_in[0];
  const float* actp  = (const float*)d_in[1];
  const float* Wih1  = (const float*)d_in[2];
  const float* Whh1  = (const float*)d_in[3];
  const float* bih1  = (const float*)d_in[4];
  const float* bhh1  = (const float*)d_in[5];
  const float* Wih2  = (const float*)d_in[6];
  const float* Whh2  = (const float*)d_in[7];
  const float* bih2  = (const float*)d_in[8];
  const float* bhh2  = (const float*)d_in[9];
  const float* W1    = (const float*)d_in[10];
  const float* b1    = (const float*)d_in[11];
  const float* W2    = (const float*)d_in[12];
  const float* b2    = (const float*)d_in[13];
  unsigned short* ws = (unsigned short*)d_ws;
  float* outp = (float*)d_out;

  actp_prep<<<NFRAG + 25, 64, 0, stream>>>(Wih1, Whh1, bih1, bhh1,
                                           Wih2, Whh2, bih2, bhh2, W1, W2, ws);
  actp_main<<<1024, 512, 0, stream>>>(tactp, actp, ws, b1, b2, outp);
}